// Round 7
// baseline (145.294 us; speedup 1.0000x reference)
//
#include <hip/hip_runtime.h>
#include <hip/hip_bf16.h>

typedef unsigned int u32;
typedef unsigned short u16;
typedef __attribute__((ext_vector_type(8))) short bf16x8;   // MFMA A/B frag (8 bf16)
typedef __attribute__((ext_vector_type(4))) float f32x4;
typedef __attribute__((ext_vector_type(16))) float f32x16;  // 32x32 MFMA C/D frag
typedef __attribute__((ext_vector_type(8))) u16 u16x8;
typedef __attribute__((ext_vector_type(2))) u32 u32x2;
typedef __attribute__((ext_vector_type(4))) u32 u32x4;

#define MFMA16(A, B, C) __builtin_amdgcn_mfma_f32_16x16x32_bf16(A, B, C, 0, 0, 0)
#define MFMA32(A, B, C) __builtin_amdgcn_mfma_f32_32x32x16_bf16(A, B, C, 0, 0, 0)

// 0.125 (1/sqrt(64)) * log2(e): folded into Q weights/bias -> scores in exp2 domain
#define C_SCALE 0.1803368801111244f

__device__ __forceinline__ u16 f2bf(float f) {   // RNE via native cast
  __hip_bfloat16 h = __float2bfloat16(f);
  u16 u;
  __builtin_memcpy(&u, &h, 2);
  return u;
}

__device__ __forceinline__ u32 pk2(float a, float b) {  // 2xbf16 pack (cvt_pk-able)
  return (u32)f2bf(a) | ((u32)f2bf(b) << 16);
}

__device__ __forceinline__ float exp2fast(float x) {
#if __has_builtin(__builtin_amdgcn_exp2f)
  return __builtin_amdgcn_exp2f(x);
#else
  return exp2f(x);
#endif
}

__device__ __forceinline__ u32x2 pl32swap(u32 a, u32 b) {
  return __builtin_amdgcn_permlane32_swap(a, b, false, false);
}

__device__ __forceinline__ void g2l16(const void* g, void* l) {
  __builtin_amdgcn_global_load_lds(
      (const __attribute__((address_space(1))) u32*)g,
      (__attribute__((address_space(3))) u32*)l, 16, 0, 0);
}

// ---------------------------------------------------------------------------
// x (fp32) -> bf16, 8 elems/thread
// ---------------------------------------------------------------------------
__global__ __launch_bounds__(256) void xcvt(const float* __restrict__ in,
                                            u16* __restrict__ out, int n8) {
  const int i = blockIdx.x * 256 + threadIdx.x;
  if (i >= n8) return;
  const float4* p = (const float4*)in + (size_t)i * 2;
  const float4 a = p[0], b = p[1];
  u16x8 o;
  o[0] = f2bf(a.x); o[1] = f2bf(a.y); o[2] = f2bf(a.z); o[3] = f2bf(a.w);
  o[4] = f2bf(b.x); o[5] = f2bf(b.y); o[6] = f2bf(b.z); o[7] = f2bf(b.w);
  *((u16x8*)out + i) = o;
}

// ---------------------------------------------------------------------------
// out[c][r] = bf16(in[r][c] * (c<scale_n ? scale : 1))  (weights -> B^T layout)
// ---------------------------------------------------------------------------
__global__ __launch_bounds__(256) void wtrans(const float* __restrict__ in,
                                              u16* __restrict__ out, int R, int C,
                                              int scale_n, float scale) {
  __shared__ float t[32][33];
  const int r0 = blockIdx.y << 5, c0 = blockIdx.x << 5;
  const int tr = threadIdx.x >> 3, tc = (threadIdx.x & 7) << 2;
  const float4 v = *(const float4*)(in + (size_t)(r0 + tr) * C + c0 + tc);
  t[tr][tc] = v.x; t[tr][tc + 1] = v.y; t[tr][tc + 2] = v.z; t[tr][tc + 3] = v.w;
  __syncthreads();
  const float s = (c0 + tr < scale_n) ? scale : 1.f;
  u32 p0 = pk2(t[tc][tr] * s, t[tc + 1][tr] * s);
  u32 p1 = pk2(t[tc + 2][tr] * s, t[tc + 3][tr] * s);
  u32* dst = (u32*)(out + (size_t)(c0 + tr) * R + r0 + tc);
  dst[0] = p0;
  dst[1] = p1;
}

// ---------------------------------------------------------------------------
// bf16 MFMA GEMM: C[M,N] = A[M,K] @ Bt[N,K]^T + bias.  128x128 tile, BK=32,
// 4 waves, global_load_lds, XOR-swizzled LDS.  (unchanged)
// ---------------------------------------------------------------------------
template <int OUT_BF16>
__global__ __launch_bounds__(256) void gemm_mfma(
    const u16* __restrict__ A, const u16* __restrict__ Bt,
    const float* __restrict__ bias, void* __restrict__ Cv, int N, int K,
    int bsn, float bsc) {
  __shared__ u16 As[128 * 32];
  __shared__ u16 Bs[128 * 32];
  const int tid = threadIdx.x;
  const int l = tid & 63, g = l >> 4, lr = l & 15;
  const int w = tid >> 6;
  const int wm = (w >> 1) << 6, wn = (w & 1) << 6;
  const int bm = blockIdx.y << 7, bn = blockIdx.x << 7;

  f32x4 acc[4][4];
  const f32x4 zero = {0.f, 0.f, 0.f, 0.f};
#pragma unroll
  for (int i = 0; i < 4; ++i)
#pragma unroll
    for (int j = 0; j < 4; ++j) acc[i][j] = zero;

  const int bi0 = tid, bi1 = 256 + tid;
  const int r0 = bi0 >> 2, lb0 = (bi0 & 3) ^ ((r0 >> 1) & 3);
  const int r1 = bi1 >> 2, lb1 = (bi1 & 3) ^ ((r1 >> 1) & 3);
  const u16* a0 = A + (size_t)(bm + r0) * K + lb0 * 8;
  const u16* a1 = A + (size_t)(bm + r1) * K + lb1 * 8;
  const u16* b0 = Bt + (size_t)(bn + r0) * K + lb0 * 8;
  const u16* b1 = Bt + (size_t)(bn + r1) * K + lb1 * 8;

  const int swA = (lr >> 1) & 3;
  const int aoff = (wm + lr) * 64 + ((g ^ swA) << 4);
  const int boff = (wn + lr) * 64 + ((g ^ swA) << 4);

  for (int k0 = 0; k0 < K; k0 += 32) {
    __syncthreads();
    g2l16(a0 + k0, (char*)As + bi0 * 16);
    g2l16(a1 + k0, (char*)As + bi1 * 16);
    g2l16(b0 + k0, (char*)Bs + bi0 * 16);
    g2l16(b1 + k0, (char*)Bs + bi1 * 16);
    __syncthreads();
    bf16x8 af[4], bfv[4];
#pragma unroll
    for (int mi = 0; mi < 4; ++mi)
      af[mi] = *(const bf16x8*)((const char*)As + aoff + mi * 1024);
#pragma unroll
    for (int ni = 0; ni < 4; ++ni)
      bfv[ni] = *(const bf16x8*)((const char*)Bs + boff + ni * 1024);
#pragma unroll
    for (int mi = 0; mi < 4; ++mi)
#pragma unroll
      for (int ni = 0; ni < 4; ++ni)
        acc[mi][ni] = MFMA16(af[mi], bfv[ni], acc[mi][ni]);
  }

  float bv[4];
#pragma unroll
  for (int ni = 0; ni < 4; ++ni) {
    const int col = bn + wn + ni * 16 + lr;
    bv[ni] = bias[col] * (col < bsn ? bsc : 1.f);
  }
  const int crow = bm + wm + (g << 2);
  const int ccol = bn + wn + lr;
  if (OUT_BF16) {
    u16* C = (u16*)Cv;
#pragma unroll
    for (int mi = 0; mi < 4; ++mi)
#pragma unroll
      for (int ni = 0; ni < 4; ++ni)
#pragma unroll
        for (int j = 0; j < 4; ++j)
          C[(size_t)(crow + mi * 16 + j) * N + ccol + ni * 16] =
              f2bf(acc[mi][ni][j] + bv[ni]);
  } else {
    float* C = (float*)Cv;
#pragma unroll
    for (int mi = 0; mi < 4; ++mi)
#pragma unroll
      for (int ni = 0; ni < 4; ++ni)
#pragma unroll
        for (int j = 0; j < 4; ++j)
          C[(size_t)(crow + mi * 16 + j) * N + ccol + ni * 16] =
              acc[mi][ni][j] + bv[ni];
  }
}

// ---------------------------------------------------------------------------
// V-transpose: qkv_b[.., 2048+h*64+d] -> vt[(b*16+h)*64+d][s]  (bf16)
// ---------------------------------------------------------------------------
__global__ __launch_bounds__(256) void vtrans(const u16* __restrict__ qkvb,
                                              u16* __restrict__ vt) {
  const int wid = (blockIdx.x << 2) + (threadIdx.x >> 6);
  const int l = threadIdx.x & 63;
  const int dc = wid & 7, st = (wid >> 3) & 31, h = (wid >> 8) & 15, b = wid >> 12;
  const int s = (st << 6) + l;
  const u16x8 v = *(const u16x8*)(qkvb + (size_t)(b * 2048 + s) * 3072 + 2048 + h * 64 + dc * 8);
  u16* dst = vt + ((size_t)(((b << 4) + h) << 6) + (dc << 3)) * 2048 + s;
#pragma unroll
  for (int j = 0; j < 8; ++j) dst[(size_t)j * 2048] = v[j];
}

// ---------------------------------------------------------------------------
// Flash attention, 32x32x16 MFMA, swapped QK^T, in-register softmax + P.
// K/V double-buffered: next tile's global_load_lds issued BEFORE compute on
// the current tile; one barrier per iteration (the implicit vmcnt drain is
// ~free since loads had the whole compute phase to land).  setprio around
// MFMA clusters (T5).  Cross-half l-reduction deferred to epilogue.
// ---------------------------------------------------------------------------
__global__ __launch_bounds__(256, 2) void attn_mfma(
    const u16* __restrict__ qkvb, const u16* __restrict__ vt,
    u16* __restrict__ attnb) {
  __shared__ u16 Qs[128 * 64];
  __shared__ u16 Ks[2][64 * 64];
  __shared__ u16 Vs[2][64 * 64];

  const int qt = blockIdx.x, head = blockIdx.y, b = blockIdx.z;
  const int tid = threadIdx.x, w = tid >> 6, l = tid & 63;
  const int lq = l & 31, hw = l >> 5;
  const size_t sb = (size_t)b * 2048;
  const f32x16 z16 = {};

  const int bi0 = tid, bi1 = 256 + tid;
  const int sr0 = bi0 >> 3, slb0 = (bi0 & 7) ^ (sr0 & 7);
  const int sr1 = bi1 >> 3, slb1 = (bi1 & 7) ^ (sr1 & 7);

  const u16* kbase = qkvb + sb * 3072 + 1024 + head * 64;
  const u16* vbase = vt + ((size_t)((b << 4) + head) << 6) * 2048;

  // per-thread staging sources (K row-major in qkv; V^T row-major in vt)
  const u16* kp0 = kbase + (size_t)sr0 * 3072 + slb0 * 8;
  const u16* kp1 = kbase + (size_t)sr1 * 3072 + slb1 * 8;
  const u16* vp0 = vbase + (size_t)sr0 * 2048 + slb0 * 8;
  const u16* vp1 = vbase + (size_t)sr1 * 2048 + slb1 * 8;

#define STAGE(buf, kt)                                                        \
  do {                                                                        \
    const size_t ko_ = (size_t)(kt) << 6;                                     \
    g2l16(kp0 + ko_ * 3072, (char*)Ks[buf] + bi0 * 16);                       \
    g2l16(kp1 + ko_ * 3072, (char*)Ks[buf] + bi1 * 16);                       \
    g2l16(vp0 + ko_, (char*)Vs[buf] + bi0 * 16);                              \
    g2l16(vp1 + ko_, (char*)Vs[buf] + bi1 * 16);                              \
  } while (0)

  // stage Q[128 q][64 d] (block-swizzle ^ (row&7)) + first K/V tile
  {
    const u16* qb = qkvb + (sb + (size_t)qt * 128) * 3072 + head * 64;
#pragma unroll
    for (int j = 0; j < 4; ++j) {
      const int qi = tid + 256 * j;
      const int r = qi >> 3, blk = (qi & 7) ^ (r & 7);
      g2l16(qb + (size_t)r * 3072 + blk * 8, (char*)Qs + qi * 16);
    }
  }
  STAGE(0, 0);
  __syncthreads();

  // Q frags (B-operand): col q = lq (abs row 32w+lq), k = d = 16dc+8hw+e
  bf16x8 qf[4];
  {
    const int row = (w << 5) + lq;
#pragma unroll
    for (int dc = 0; dc < 4; ++dc)
      qf[dc] = *(const bf16x8*)((const char*)Qs + row * 128 +
                                (((2 * dc + hw) ^ (row & 7)) << 4));
  }

  float m_run = -1e30f, l_run = 0.f;
  f32x16 o0 = z16, o1 = z16;

  for (int kt = 0; kt < 32; ++kt) {
    const int cur = kt & 1;
    if (kt < 31) STAGE(cur ^ 1, kt + 1);  // prefetch overlaps compute below

    // QK^T (swapped): st[kb] = S^T[keys 32kb..+31][q 32 cols], exp2 domain
    f32x16 st0 = z16, st1 = z16;
    __builtin_amdgcn_s_setprio(1);
#pragma unroll
    for (int dc = 0; dc < 4; ++dc) {
      const int blk = 2 * dc + hw;
      const bf16x8 k0 = *(const bf16x8*)((const char*)Ks[cur] + lq * 128 +
                                         ((blk ^ (lq & 7)) << 4));
      st0 = MFMA32(k0, qf[dc], st0);
      const bf16x8 k1 = *(const bf16x8*)((const char*)Ks[cur] + (32 + lq) * 128 +
                                         ((blk ^ (lq & 7)) << 4));
      st1 = MFMA32(k1, qf[dc], st1);
    }
    __builtin_amdgcn_s_setprio(0);

    // in-register online softmax for q = lq (cross-half via permlane32_swap)
    float mx = st0[0];
#pragma unroll
    for (int i = 1; i < 16; ++i) mx = fmaxf(mx, st0[i]);
#pragma unroll
    for (int i = 0; i < 16; ++i) mx = fmaxf(mx, st1[i]);
    {
      const u32x2 r = pl32swap(__float_as_uint(mx), __float_as_uint(mx));
      mx = fmaxf(__uint_as_float(r.x), __uint_as_float(r.y));
    }
    if (!__all(mx - m_run <= 8.f)) {   // defer-max: rescale only when max grows
      const float m_new = fmaxf(m_run, mx);
      const float resc = exp2fast(m_run - m_new);
      float rs[16];
#pragma unroll
      for (int r = 0; r < 16; ++r)
        rs[r] = __shfl(resc, (r & 3) + 8 * (r >> 2) + 4 * hw);
#pragma unroll
      for (int r = 0; r < 16; ++r) { o0[r] *= rs[r]; o1[r] *= rs[r]; }
      l_run *= resc;
      m_run = m_new;
    }
    float lsum = 0.f;
#pragma unroll
    for (int i = 0; i < 16; ++i) { st0[i] = exp2fast(st0[i] - m_run); lsum += st0[i]; }
#pragma unroll
    for (int i = 0; i < 16; ++i) { st1[i] = exp2fast(st1[i] - m_run); lsum += st1[i]; }
    l_run += lsum;  // per-half partial; combined once in epilogue

    // pack P -> PV A-frags: pa[kc] elem e holds key 16kc+8hw+e for q=lq.
    bf16x8 pa[4];
#pragma unroll
    for (int kc = 0; kc < 4; ++kc) {
      const f32x16 s = (kc < 2) ? st0 : st1;
      const int q0 = (kc & 1) * 8;
      const u32 W01 = pk2(s[q0 + 0], s[q0 + 1]);
      const u32 W23 = pk2(s[q0 + 2], s[q0 + 3]);
      const u32 W45 = pk2(s[q0 + 4], s[q0 + 5]);
      const u32 W67 = pk2(s[q0 + 6], s[q0 + 7]);
      const u32x2 rA = pl32swap(W01, W45);
      const u32x2 rB = pl32swap(W23, W67);
      const u32x4 wds = {rA.x, rB.x, rA.y, rB.y};
      pa[kc] = __builtin_bit_cast(bf16x8, wds);
    }

    // PV: O[32q][64d] += P @ V.  B-frag: col d = 32nb+lq, k = key 16kc+8hw+e
    __builtin_amdgcn_s_setprio(1);
#pragma unroll
    for (int kc = 0; kc < 4; ++kc) {
      const int blk = 2 * kc + hw;
      const bf16x8 v0 = *(const bf16x8*)((const char*)Vs[cur] + lq * 128 +
                                         ((blk ^ (lq & 7)) << 4));
      o0 = MFMA32(pa[kc], v0, o0);
      const bf16x8 v1 = *(const bf16x8*)((const char*)Vs[cur] + (32 + lq) * 128 +
                                         ((blk ^ (lq & 7)) << 4));
      o1 = MFMA32(pa[kc], v1, o1);
    }
    __builtin_amdgcn_s_setprio(0);

    // end-of-iter: waits my prefetch (landed during compute) + all waves done
    __syncthreads();
  }
#undef STAGE

  // combine per-half l partials, then epilogue
  {
    const u32x2 r = pl32swap(__float_as_uint(l_run), __float_as_uint(l_run));
    l_run = __uint_as_float(r.x) + __uint_as_float(r.y);
  }
  const float invl = 1.f / l_run;
  u16* ob = attnb + (sb + (size_t)qt * 128 + (w << 5)) * 1024 + head * 64;
#pragma unroll
  for (int r = 0; r < 16; ++r) {
    const int qo = (r & 3) + 8 * (r >> 2) + 4 * hw;
    const float iv = __shfl(invl, qo);
    ob[(size_t)qo * 1024 + lq] = f2bf(o0[r] * iv);
    ob[(size_t)qo * 1024 + 32 + lq] = f2bf(o1[r] * iv);
  }
}

// ---------------------------------------------------------------------------
extern "C" void kernel_launch(void* const* d_in, const int* in_sizes, int n_in,
                              void* d_out, int out_size, void* d_ws, size_t ws_size,
                              hipStream_t stream) {
  const float* x     = (const float*)d_in[0];  // [2,2048,1024]
  const float* w_qkv = (const float*)d_in[1];  // [1024,3072]
  const float* b_qkv = (const float*)d_in[2];  // [3072]
  const float* w_o   = (const float*)d_in[3];  // [1024,1024]
  const float* b_o   = (const float*)d_in[4];  // [1024]
  float* out = (float*)d_out;

  // workspace (bf16), 56 MB total
  u16* xb    = (u16*)d_ws;                       // 4096*1024
  u16* wqkvt = xb + (size_t)4096 * 1024;         // 3072*1024 (B^T)
  u16* wot   = wqkvt + (size_t)3072 * 1024;      // 1024*1024 (B^T)
  u16* qkvb  = wot + (size_t)1024 * 1024;        // 4096*3072
  u16* vtb   = qkvb + (size_t)4096 * 3072;       // 2*16*64*2048
  u16* attnb = vtb + (size_t)2 * 16 * 64 * 2048; // 4096*1024

  xcvt<<<dim3(2048), dim3(256), 0, stream>>>(x, xb, 4096 * 1024 / 8);
  // Q-columns (first 1024 of 3072) pre-scaled by 0.125*log2e -> exp2-domain scores
  wtrans<<<dim3(96, 32), dim3(256), 0, stream>>>(w_qkv, wqkvt, 1024, 3072, 1024, C_SCALE);
  wtrans<<<dim3(32, 32), dim3(256), 0, stream>>>(w_o, wot, 1024, 1024, 0, 1.f);

  gemm_mfma<1><<<dim3(24, 32), dim3(256), 0, stream>>>(xb, wqkvt, b_qkv, qkvb, 3072, 1024, 1024, C_SCALE);

  vtrans<<<dim3(2048), dim3(256), 0, stream>>>(qkvb, vtb);
  attn_mfma<<<dim3(16, 16, 2), dim3(256), 0, stream>>>(qkvb, vtb, attnb);

  gemm_mfma<0><<<dim3(8, 32), dim3(256), 0, stream>>>(attnb, wot, b_o, out, 1024, 1024, 0, 1.f);
}

// Round 8
// 141.758 us; speedup vs baseline: 1.0249x; 1.0249x over previous
//
#include <hip/hip_runtime.h>
#include <hip/hip_bf16.h>

typedef unsigned int u32;
typedef unsigned short u16;
typedef __attribute__((ext_vector_type(8))) short bf16x8;   // MFMA A/B frag (8 bf16)
typedef __attribute__((ext_vector_type(4))) float f32x4;
typedef __attribute__((ext_vector_type(16))) float f32x16;  // 32x32 MFMA C/D frag
typedef __attribute__((ext_vector_type(8))) u16 u16x8;
typedef __attribute__((ext_vector_type(2))) u32 u32x2;
typedef __attribute__((ext_vector_type(4))) u32 u32x4;

#define MFMA16(A, B, C) __builtin_amdgcn_mfma_f32_16x16x32_bf16(A, B, C, 0, 0, 0)
#define MFMA32(A, B, C) __builtin_amdgcn_mfma_f32_32x32x16_bf16(A, B, C, 0, 0, 0)

// 0.125 (1/sqrt(64)) * log2(e): folded into Q weights/bias -> scores in exp2 domain
#define C_SCALE 0.1803368801111244f

__device__ __forceinline__ u16 f2bf(float f) {   // RNE via native cast
  __hip_bfloat16 h = __float2bfloat16(f);
  u16 u;
  __builtin_memcpy(&u, &h, 2);
  return u;
}

__device__ __forceinline__ u32 pk2(float a, float b) {  // 2xbf16 pack (cvt_pk-able)
  return (u32)f2bf(a) | ((u32)f2bf(b) << 16);
}

__device__ __forceinline__ float exp2fast(float x) {
#if __has_builtin(__builtin_amdgcn_exp2f)
  return __builtin_amdgcn_exp2f(x);
#else
  return exp2f(x);
#endif
}

__device__ __forceinline__ u32x2 pl32swap(u32 a, u32 b) {
  return __builtin_amdgcn_permlane32_swap(a, b, false, false);
}

__device__ __forceinline__ void g2l16(const void* g, void* l) {
  __builtin_amdgcn_global_load_lds(
      (const __attribute__((address_space(1))) u32*)g,
      (__attribute__((address_space(3))) u32*)l, 16, 0, 0);
}

// ---------------------------------------------------------------------------
// x (fp32) -> bf16, 8 elems/thread
// ---------------------------------------------------------------------------
__global__ __launch_bounds__(256) void xcvt(const float* __restrict__ in,
                                            u16* __restrict__ out, int n8) {
  const int i = blockIdx.x * 256 + threadIdx.x;
  if (i >= n8) return;
  const float4* p = (const float4*)in + (size_t)i * 2;
  const float4 a = p[0], b = p[1];
  u16x8 o;
  o[0] = f2bf(a.x); o[1] = f2bf(a.y); o[2] = f2bf(a.z); o[3] = f2bf(a.w);
  o[4] = f2bf(b.x); o[5] = f2bf(b.y); o[6] = f2bf(b.z); o[7] = f2bf(b.w);
  *((u16x8*)out + i) = o;
}

// ---------------------------------------------------------------------------
// out[c][r] = bf16(in[r][c] * (c<scale_n ? scale : 1))  (weights -> B^T layout)
// ---------------------------------------------------------------------------
__global__ __launch_bounds__(256) void wtrans(const float* __restrict__ in,
                                              u16* __restrict__ out, int R, int C,
                                              int scale_n, float scale) {
  __shared__ float t[32][33];
  const int r0 = blockIdx.y << 5, c0 = blockIdx.x << 5;
  const int tr = threadIdx.x >> 3, tc = (threadIdx.x & 7) << 2;
  const float4 v = *(const float4*)(in + (size_t)(r0 + tr) * C + c0 + tc);
  t[tr][tc] = v.x; t[tr][tc + 1] = v.y; t[tr][tc + 2] = v.z; t[tr][tc + 3] = v.w;
  __syncthreads();
  const float s = (c0 + tr < scale_n) ? scale : 1.f;
  u32 p0 = pk2(t[tc][tr] * s, t[tc + 1][tr] * s);
  u32 p1 = pk2(t[tc + 2][tr] * s, t[tc + 3][tr] * s);
  u32* dst = (u32*)(out + (size_t)(c0 + tr) * R + r0 + tc);
  dst[0] = p0;
  dst[1] = p1;
}

// ---------------------------------------------------------------------------
// bf16 MFMA GEMM: C[M,N] = A[M,K] @ Bt[N,K]^T + bias.  128x128 tile, BK=32,
// 4 waves, global_load_lds, XOR-swizzled LDS.  (unchanged)
// ---------------------------------------------------------------------------
template <int OUT_BF16>
__global__ __launch_bounds__(256) void gemm_mfma(
    const u16* __restrict__ A, const u16* __restrict__ Bt,
    const float* __restrict__ bias, void* __restrict__ Cv, int N, int K,
    int bsn, float bsc) {
  __shared__ u16 As[128 * 32];
  __shared__ u16 Bs[128 * 32];
  const int tid = threadIdx.x;
  const int l = tid & 63, g = l >> 4, lr = l & 15;
  const int w = tid >> 6;
  const int wm = (w >> 1) << 6, wn = (w & 1) << 6;
  const int bm = blockIdx.y << 7, bn = blockIdx.x << 7;

  f32x4 acc[4][4];
  const f32x4 zero = {0.f, 0.f, 0.f, 0.f};
#pragma unroll
  for (int i = 0; i < 4; ++i)
#pragma unroll
    for (int j = 0; j < 4; ++j) acc[i][j] = zero;

  const int bi0 = tid, bi1 = 256 + tid;
  const int r0 = bi0 >> 2, lb0 = (bi0 & 3) ^ ((r0 >> 1) & 3);
  const int r1 = bi1 >> 2, lb1 = (bi1 & 3) ^ ((r1 >> 1) & 3);
  const u16* a0 = A + (size_t)(bm + r0) * K + lb0 * 8;
  const u16* a1 = A + (size_t)(bm + r1) * K + lb1 * 8;
  const u16* b0 = Bt + (size_t)(bn + r0) * K + lb0 * 8;
  const u16* b1 = Bt + (size_t)(bn + r1) * K + lb1 * 8;

  const int swA = (lr >> 1) & 3;
  const int aoff = (wm + lr) * 64 + ((g ^ swA) << 4);
  const int boff = (wn + lr) * 64 + ((g ^ swA) << 4);

  for (int k0 = 0; k0 < K; k0 += 32) {
    __syncthreads();
    g2l16(a0 + k0, (char*)As + bi0 * 16);
    g2l16(a1 + k0, (char*)As + bi1 * 16);
    g2l16(b0 + k0, (char*)Bs + bi0 * 16);
    g2l16(b1 + k0, (char*)Bs + bi1 * 16);
    __syncthreads();
    bf16x8 af[4], bfv[4];
#pragma unroll
    for (int mi = 0; mi < 4; ++mi)
      af[mi] = *(const bf16x8*)((const char*)As + aoff + mi * 1024);
#pragma unroll
    for (int ni = 0; ni < 4; ++ni)
      bfv[ni] = *(const bf16x8*)((const char*)Bs + boff + ni * 1024);
#pragma unroll
    for (int mi = 0; mi < 4; ++mi)
#pragma unroll
      for (int ni = 0; ni < 4; ++ni)
        acc[mi][ni] = MFMA16(af[mi], bfv[ni], acc[mi][ni]);
  }

  float bv[4];
#pragma unroll
  for (int ni = 0; ni < 4; ++ni) {
    const int col = bn + wn + ni * 16 + lr;
    bv[ni] = bias[col] * (col < bsn ? bsc : 1.f);
  }
  const int crow = bm + wm + (g << 2);
  const int ccol = bn + wn + lr;
  if (OUT_BF16) {
    u16* C = (u16*)Cv;
#pragma unroll
    for (int mi = 0; mi < 4; ++mi)
#pragma unroll
      for (int ni = 0; ni < 4; ++ni)
#pragma unroll
        for (int j = 0; j < 4; ++j)
          C[(size_t)(crow + mi * 16 + j) * N + ccol + ni * 16] =
              f2bf(acc[mi][ni][j] + bv[ni]);
  } else {
    float* C = (float*)Cv;
#pragma unroll
    for (int mi = 0; mi < 4; ++mi)
#pragma unroll
      for (int ni = 0; ni < 4; ++ni)
#pragma unroll
        for (int j = 0; j < 4; ++j)
          C[(size_t)(crow + mi * 16 + j) * N + ccol + ni * 16] =
              acc[mi][ni][j] + bv[ni];
  }
}

// ---------------------------------------------------------------------------
// V-transpose: qkv_b[.., 2048+h*64+d] -> vt[(b*16+h)*64+d][s]  (bf16)
// ---------------------------------------------------------------------------
__global__ __launch_bounds__(256) void vtrans(const u16* __restrict__ qkvb,
                                              u16* __restrict__ vt) {
  const int wid = (blockIdx.x << 2) + (threadIdx.x >> 6);
  const int l = threadIdx.x & 63;
  const int dc = wid & 7, st = (wid >> 3) & 31, h = (wid >> 8) & 15, b = wid >> 12;
  const int s = (st << 6) + l;
  const u16x8 v = *(const u16x8*)(qkvb + (size_t)(b * 2048 + s) * 3072 + 2048 + h * 64 + dc * 8);
  u16* dst = vt + ((size_t)(((b << 4) + h) << 6) + (dc << 3)) * 2048 + s;
#pragma unroll
  for (int j = 0; j < 8; ++j) dst[(size_t)j * 2048] = v[j];
}

// ---------------------------------------------------------------------------
// Flash attention, 32x32x16 MFMA, swapped QK^T, in-register softmax + P.
// Round-5 schedule (stage -> drain -> compute) with KVBLK=128: two 64-key
// sub-tiles staged per barrier pair, computed back-to-back.  16 barrier
// pairs instead of 32 -> half the exposed-drain / sync-jitter cost.
// ---------------------------------------------------------------------------
__global__ __launch_bounds__(256, 2) void attn_mfma(
    const u16* __restrict__ qkvb, const u16* __restrict__ vt,
    u16* __restrict__ attnb) {
  __shared__ u16 Qs[128 * 64];
  __shared__ u16 Ks2[2][64 * 64];
  __shared__ u16 Vs2[2][64 * 64];

  const int qt = blockIdx.x, head = blockIdx.y, b = blockIdx.z;
  const int tid = threadIdx.x, w = tid >> 6, l = tid & 63;
  const int lq = l & 31, hw = l >> 5;
  const size_t sb = (size_t)b * 2048;
  const f32x16 z16 = {};

  const int bi0 = tid, bi1 = 256 + tid;
  const int sr0 = bi0 >> 3, slb0 = (bi0 & 7) ^ (sr0 & 7);
  const int sr1 = bi1 >> 3, slb1 = (bi1 & 7) ^ (sr1 & 7);

  const u16* kbase = qkvb + sb * 3072 + 1024 + head * 64;
  const u16* vbase = vt + ((size_t)((b << 4) + head) << 6) * 2048;

  // per-thread staging sources (K row-major in qkv; V^T row-major in vt)
  const u16* kp0 = kbase + (size_t)sr0 * 3072 + slb0 * 8;
  const u16* kp1 = kbase + (size_t)sr1 * 3072 + slb1 * 8;
  const u16* vp0 = vbase + (size_t)sr0 * 2048 + slb0 * 8;
  const u16* vp1 = vbase + (size_t)sr1 * 2048 + slb1 * 8;

  // stage Q[128 q][64 d] (block-swizzle ^ (row&7))
  {
    const u16* qb = qkvb + (sb + (size_t)qt * 128) * 3072 + head * 64;
#pragma unroll
    for (int j = 0; j < 4; ++j) {
      const int qi = tid + 256 * j;
      const int r = qi >> 3, blk = (qi & 7) ^ (r & 7);
      g2l16(qb + (size_t)r * 3072 + blk * 8, (char*)Qs + qi * 16);
    }
  }
  __syncthreads();

  // Q frags (B-operand): col q = lq (abs row 32w+lq), k = d = 16dc+8hw+e
  bf16x8 qf[4];
  {
    const int row = (w << 5) + lq;
#pragma unroll
    for (int dc = 0; dc < 4; ++dc)
      qf[dc] = *(const bf16x8*)((const char*)Qs + row * 128 +
                                (((2 * dc + hw) ^ (row & 7)) << 4));
  }

  float m_run = -1e30f, l_run = 0.f;
  f32x16 o0 = z16, o1 = z16;

  for (int kt = 0; kt < 16; ++kt) {
    const size_t ko = (size_t)kt << 7;  // 128 keys per barrier pair
    __syncthreads();                    // all waves done reading prev tiles
    g2l16(kp0 + ko * 3072, (char*)Ks2[0] + bi0 * 16);
    g2l16(kp1 + ko * 3072, (char*)Ks2[0] + bi1 * 16);
    g2l16(kp0 + (ko + 64) * 3072, (char*)Ks2[1] + bi0 * 16);
    g2l16(kp1 + (ko + 64) * 3072, (char*)Ks2[1] + bi1 * 16);
    g2l16(vp0 + ko, (char*)Vs2[0] + bi0 * 16);
    g2l16(vp1 + ko, (char*)Vs2[0] + bi1 * 16);
    g2l16(vp0 + ko + 64, (char*)Vs2[1] + bi0 * 16);
    g2l16(vp1 + ko + 64, (char*)Vs2[1] + bi1 * 16);
    __syncthreads();                    // drain staging

#pragma unroll
    for (int sub = 0; sub < 2; ++sub) {
      const char* Kt = (const char*)Ks2[sub];
      const char* Vt = (const char*)Vs2[sub];

      // QK^T (swapped): st = S^T[keys 64sub+32kb..][q 32 cols], exp2 domain
      f32x16 st0 = z16, st1 = z16;
#pragma unroll
      for (int dc = 0; dc < 4; ++dc) {
        const int blk = 2 * dc + hw;
        const bf16x8 k0 = *(const bf16x8*)(Kt + lq * 128 + ((blk ^ (lq & 7)) << 4));
        st0 = MFMA32(k0, qf[dc], st0);
        const bf16x8 k1 = *(const bf16x8*)(Kt + (32 + lq) * 128 + ((blk ^ (lq & 7)) << 4));
        st1 = MFMA32(k1, qf[dc], st1);
      }

      // in-register online softmax for q = lq (cross-half via permlane32_swap)
      float mx = st0[0];
#pragma unroll
      for (int i = 1; i < 16; ++i) mx = fmaxf(mx, st0[i]);
#pragma unroll
      for (int i = 0; i < 16; ++i) mx = fmaxf(mx, st1[i]);
      {
        const u32x2 r = pl32swap(__float_as_uint(mx), __float_as_uint(mx));
        mx = fmaxf(__uint_as_float(r.x), __uint_as_float(r.y));
      }
      if (!__all(mx - m_run <= 8.f)) {  // defer-max: rescale only when max grows
        const float m_new = fmaxf(m_run, mx);
        const float resc = exp2fast(m_run - m_new);
        float rs[16];
#pragma unroll
        for (int r = 0; r < 16; ++r)
          rs[r] = __shfl(resc, (r & 3) + 8 * (r >> 2) + 4 * hw);
#pragma unroll
        for (int r = 0; r < 16; ++r) { o0[r] *= rs[r]; o1[r] *= rs[r]; }
        l_run *= resc;
        m_run = m_new;
      }
      float lsum = 0.f;
#pragma unroll
      for (int i = 0; i < 16; ++i) { st0[i] = exp2fast(st0[i] - m_run); lsum += st0[i]; }
#pragma unroll
      for (int i = 0; i < 16; ++i) { st1[i] = exp2fast(st1[i] - m_run); lsum += st1[i]; }
      l_run += lsum;  // per-half partial; combined once in epilogue

      // pack P -> PV A-frags: pa[kc] elem e holds key 16kc+8hw+e for q=lq.
      bf16x8 pa[4];
#pragma unroll
      for (int kc = 0; kc < 4; ++kc) {
        const f32x16 s = (kc < 2) ? st0 : st1;
        const int q0 = (kc & 1) * 8;
        const u32 W01 = pk2(s[q0 + 0], s[q0 + 1]);
        const u32 W23 = pk2(s[q0 + 2], s[q0 + 3]);
        const u32 W45 = pk2(s[q0 + 4], s[q0 + 5]);
        const u32 W67 = pk2(s[q0 + 6], s[q0 + 7]);
        const u32x2 rA = pl32swap(W01, W45);
        const u32x2 rB = pl32swap(W23, W67);
        const u32x4 wds = {rA.x, rB.x, rA.y, rB.y};
        pa[kc] = __builtin_bit_cast(bf16x8, wds);
      }

      // PV: O[32q][64d] += P @ V.  B-frag: col d = 32nb+lq, k = key 16kc+8hw+e
#pragma unroll
      for (int kc = 0; kc < 4; ++kc) {
        const int blk = 2 * kc + hw;
        const bf16x8 v0 = *(const bf16x8*)(Vt + lq * 128 + ((blk ^ (lq & 7)) << 4));
        o0 = MFMA32(pa[kc], v0, o0);
        const bf16x8 v1 = *(const bf16x8*)(Vt + (32 + lq) * 128 + ((blk ^ (lq & 7)) << 4));
        o1 = MFMA32(pa[kc], v1, o1);
      }
    }
  }

  // combine per-half l partials, then epilogue
  {
    const u32x2 r = pl32swap(__float_as_uint(l_run), __float_as_uint(l_run));
    l_run = __uint_as_float(r.x) + __uint_as_float(r.y);
  }
  const float invl = 1.f / l_run;
  u16* ob = attnb + (sb + (size_t)qt * 128 + (w << 5)) * 1024 + head * 64;
#pragma unroll
  for (int r = 0; r < 16; ++r) {
    const int qo = (r & 3) + 8 * (r >> 2) + 4 * hw;
    const float iv = __shfl(invl, qo);
    ob[(size_t)qo * 1024 + lq] = f2bf(o0[r] * iv);
    ob[(size_t)qo * 1024 + 32 + lq] = f2bf(o1[r] * iv);
  }
}

// ---------------------------------------------------------------------------
extern "C" void kernel_launch(void* const* d_in, const int* in_sizes, int n_in,
                              void* d_out, int out_size, void* d_ws, size_t ws_size,
                              hipStream_t stream) {
  const float* x     = (const float*)d_in[0];  // [2,2048,1024]
  const float* w_qkv = (const float*)d_in[1];  // [1024,3072]
  const float* b_qkv = (const float*)d_in[2];  // [3072]
  const float* w_o   = (const float*)d_in[3];  // [1024,1024]
  const float* b_o   = (const float*)d_in[4];  // [1024]
  float* out = (float*)d_out;

  // workspace (bf16), 56 MB total
  u16* xb    = (u16*)d_ws;                       // 4096*1024
  u16* wqkvt = xb + (size_t)4096 * 1024;         // 3072*1024 (B^T)
  u16* wot   = wqkvt + (size_t)3072 * 1024;      // 1024*1024 (B^T)
  u16* qkvb  = wot + (size_t)1024 * 1024;        // 4096*3072
  u16* vtb   = qkvb + (size_t)4096 * 3072;       // 2*16*64*2048
  u16* attnb = vtb + (size_t)2 * 16 * 64 * 2048; // 4096*1024

  xcvt<<<dim3(2048), dim3(256), 0, stream>>>(x, xb, 4096 * 1024 / 8);
  // Q-columns (first 1024 of 3072) pre-scaled by 0.125*log2e -> exp2-domain scores
  wtrans<<<dim3(96, 32), dim3(256), 0, stream>>>(w_qkv, wqkvt, 1024, 3072, 1024, C_SCALE);
  wtrans<<<dim3(32, 32), dim3(256), 0, stream>>>(w_o, wot, 1024, 1024, 0, 1.f);

  gemm_mfma<1><<<dim3(24, 32), dim3(256), 0, stream>>>(xb, wqkvt, b_qkv, qkvb, 3072, 1024, 1024, C_SCALE);

  vtrans<<<dim3(2048), dim3(256), 0, stream>>>(qkvb, vtb);
  attn_mfma<<<dim3(16, 16, 2), dim3(256), 0, stream>>>(qkvb, vtb, attnb);

  gemm_mfma<0><<<dim3(8, 32), dim3(256), 0, stream>>>(attnb, wot, b_o, out, 1024, 1024, 0, 1.f);
}

// Round 9
// 139.382 us; speedup vs baseline: 1.0424x; 1.0170x over previous
//
#include <hip/hip_runtime.h>
#include <hip/hip_bf16.h>

typedef unsigned int u32;
typedef unsigned short u16;
typedef __attribute__((ext_vector_type(8))) short bf16x8;   // MFMA A/B frag (8 bf16)
typedef __attribute__((ext_vector_type(4))) float f32x4;
typedef __attribute__((ext_vector_type(16))) float f32x16;  // 32x32 MFMA C/D frag
typedef __attribute__((ext_vector_type(8))) u16 u16x8;
typedef __attribute__((ext_vector_type(2))) u32 u32x2;
typedef __attribute__((ext_vector_type(4))) u32 u32x4;

#define MFMA16(A, B, C) __builtin_amdgcn_mfma_f32_16x16x32_bf16(A, B, C, 0, 0, 0)
#define MFMA32(A, B, C) __builtin_amdgcn_mfma_f32_32x32x16_bf16(A, B, C, 0, 0, 0)

// 0.125 (1/sqrt(64)) * log2(e): folded into Q weights/bias -> scores in exp2 domain
#define C_SCALE 0.1803368801111244f

__device__ __forceinline__ u16 f2bf(float f) {   // RNE via native cast
  __hip_bfloat16 h = __float2bfloat16(f);
  u16 u;
  __builtin_memcpy(&u, &h, 2);
  return u;
}

__device__ __forceinline__ u32 pk2(float a, float b) {  // 2xbf16 pack (cvt_pk-able)
  return (u32)f2bf(a) | ((u32)f2bf(b) << 16);
}

__device__ __forceinline__ float exp2fast(float x) {
#if __has_builtin(__builtin_amdgcn_exp2f)
  return __builtin_amdgcn_exp2f(x);
#else
  return exp2f(x);
#endif
}

__device__ __forceinline__ u32x2 pl32swap(u32 a, u32 b) {
  return __builtin_amdgcn_permlane32_swap(a, b, false, false);
}

__device__ __forceinline__ void g2l16(const void* g, void* l) {
  __builtin_amdgcn_global_load_lds(
      (const __attribute__((address_space(1))) u32*)g,
      (__attribute__((address_space(3))) u32*)l, 16, 0, 0);
}

// ---------------------------------------------------------------------------
// x (fp32) -> bf16, 8 elems/thread
// ---------------------------------------------------------------------------
__global__ __launch_bounds__(256) void xcvt(const float* __restrict__ in,
                                            u16* __restrict__ out, int n8) {
  const int i = blockIdx.x * 256 + threadIdx.x;
  if (i >= n8) return;
  const float4* p = (const float4*)in + (size_t)i * 2;
  const float4 a = p[0], b = p[1];
  u16x8 o;
  o[0] = f2bf(a.x); o[1] = f2bf(a.y); o[2] = f2bf(a.z); o[3] = f2bf(a.w);
  o[4] = f2bf(b.x); o[5] = f2bf(b.y); o[6] = f2bf(b.z); o[7] = f2bf(b.w);
  *((u16x8*)out + i) = o;
}

// ---------------------------------------------------------------------------
// out[c][r] = bf16(in[r][c] * (c<scale_n ? scale : 1))  (weights -> B^T layout)
// ---------------------------------------------------------------------------
__global__ __launch_bounds__(256) void wtrans(const float* __restrict__ in,
                                              u16* __restrict__ out, int R, int C,
                                              int scale_n, float scale) {
  __shared__ float t[32][33];
  const int r0 = blockIdx.y << 5, c0 = blockIdx.x << 5;
  const int tr = threadIdx.x >> 3, tc = (threadIdx.x & 7) << 2;
  const float4 v = *(const float4*)(in + (size_t)(r0 + tr) * C + c0 + tc);
  t[tr][tc] = v.x; t[tr][tc + 1] = v.y; t[tr][tc + 2] = v.z; t[tr][tc + 3] = v.w;
  __syncthreads();
  const float s = (c0 + tr < scale_n) ? scale : 1.f;
  u32 p0 = pk2(t[tc][tr] * s, t[tc + 1][tr] * s);
  u32 p1 = pk2(t[tc + 2][tr] * s, t[tc + 3][tr] * s);
  u32* dst = (u32*)(out + (size_t)(c0 + tr) * R + r0 + tc);
  dst[0] = p0;
  dst[1] = p1;
}

// ---------------------------------------------------------------------------
// bf16 MFMA GEMM: C[M,N] = A[M,K] @ Bt[N,K]^T + bias.  128x128 tile, BK=32,
// 4 waves, global_load_lds, XOR-swizzled LDS.  (unchanged)
// ---------------------------------------------------------------------------
template <int OUT_BF16>
__global__ __launch_bounds__(256) void gemm_mfma(
    const u16* __restrict__ A, const u16* __restrict__ Bt,
    const float* __restrict__ bias, void* __restrict__ Cv, int N, int K,
    int bsn, float bsc) {
  __shared__ u16 As[128 * 32];
  __shared__ u16 Bs[128 * 32];
  const int tid = threadIdx.x;
  const int l = tid & 63, g = l >> 4, lr = l & 15;
  const int w = tid >> 6;
  const int wm = (w >> 1) << 6, wn = (w & 1) << 6;
  const int bm = blockIdx.y << 7, bn = blockIdx.x << 7;

  f32x4 acc[4][4];
  const f32x4 zero = {0.f, 0.f, 0.f, 0.f};
#pragma unroll
  for (int i = 0; i < 4; ++i)
#pragma unroll
    for (int j = 0; j < 4; ++j) acc[i][j] = zero;

  const int bi0 = tid, bi1 = 256 + tid;
  const int r0 = bi0 >> 2, lb0 = (bi0 & 3) ^ ((r0 >> 1) & 3);
  const int r1 = bi1 >> 2, lb1 = (bi1 & 3) ^ ((r1 >> 1) & 3);
  const u16* a0 = A + (size_t)(bm + r0) * K + lb0 * 8;
  const u16* a1 = A + (size_t)(bm + r1) * K + lb1 * 8;
  const u16* b0 = Bt + (size_t)(bn + r0) * K + lb0 * 8;
  const u16* b1 = Bt + (size_t)(bn + r1) * K + lb1 * 8;

  const int swA = (lr >> 1) & 3;
  const int aoff = (wm + lr) * 64 + ((g ^ swA) << 4);
  const int boff = (wn + lr) * 64 + ((g ^ swA) << 4);

  for (int k0 = 0; k0 < K; k0 += 32) {
    __syncthreads();
    g2l16(a0 + k0, (char*)As + bi0 * 16);
    g2l16(a1 + k0, (char*)As + bi1 * 16);
    g2l16(b0 + k0, (char*)Bs + bi0 * 16);
    g2l16(b1 + k0, (char*)Bs + bi1 * 16);
    __syncthreads();
    bf16x8 af[4], bfv[4];
#pragma unroll
    for (int mi = 0; mi < 4; ++mi)
      af[mi] = *(const bf16x8*)((const char*)As + aoff + mi * 1024);
#pragma unroll
    for (int ni = 0; ni < 4; ++ni)
      bfv[ni] = *(const bf16x8*)((const char*)Bs + boff + ni * 1024);
#pragma unroll
    for (int mi = 0; mi < 4; ++mi)
#pragma unroll
      for (int ni = 0; ni < 4; ++ni)
        acc[mi][ni] = MFMA16(af[mi], bfv[ni], acc[mi][ni]);
  }

  float bv[4];
#pragma unroll
  for (int ni = 0; ni < 4; ++ni) {
    const int col = bn + wn + ni * 16 + lr;
    bv[ni] = bias[col] * (col < bsn ? bsc : 1.f);
  }
  const int crow = bm + wm + (g << 2);
  const int ccol = bn + wn + lr;
  if (OUT_BF16) {
    u16* C = (u16*)Cv;
#pragma unroll
    for (int mi = 0; mi < 4; ++mi)
#pragma unroll
      for (int ni = 0; ni < 4; ++ni)
#pragma unroll
        for (int j = 0; j < 4; ++j)
          C[(size_t)(crow + mi * 16 + j) * N + ccol + ni * 16] =
              f2bf(acc[mi][ni][j] + bv[ni]);
  } else {
    float* C = (float*)Cv;
#pragma unroll
    for (int mi = 0; mi < 4; ++mi)
#pragma unroll
      for (int ni = 0; ni < 4; ++ni)
#pragma unroll
        for (int j = 0; j < 4; ++j)
          C[(size_t)(crow + mi * 16 + j) * N + ccol + ni * 16] =
              acc[mi][ni][j] + bv[ni];
  }
}

// ---------------------------------------------------------------------------
// V-transpose: qkv_b[.., 2048+h*64+d] -> vt[(b*16+h)*64+d][s]  (bf16)
// ---------------------------------------------------------------------------
__global__ __launch_bounds__(256) void vtrans(const u16* __restrict__ qkvb,
                                              u16* __restrict__ vt) {
  const int wid = (blockIdx.x << 2) + (threadIdx.x >> 6);
  const int l = threadIdx.x & 63;
  const int dc = wid & 7, st = (wid >> 3) & 31, h = (wid >> 8) & 15, b = wid >> 12;
  const int s = (st << 6) + l;
  const u16x8 v = *(const u16x8*)(qkvb + (size_t)(b * 2048 + s) * 3072 + 2048 + h * 64 + dc * 8);
  u16* dst = vt + ((size_t)(((b << 4) + h) << 6) + (dc << 3)) * 2048 + s;
#pragma unroll
  for (int j = 0; j < 8; ++j) dst[(size_t)j * 2048] = v[j];
}

// ---------------------------------------------------------------------------
// Flash attention, 32x32x16 MFMA, swapped QK^T, in-register softmax + P.
// KVBLK=128 per barrier pair; BOTH 64-key sub-tiles' QK^T computed up front
// (16 independent MFMAs), one softmax window per 128 keys, and the tail
// ordered exp/pack(sub0) -> PV(sub0) -> exp/pack(sub1) -> PV(sub1) so sub1's
// VALU work co-issues under PV(sub0)'s MFMAs (intra-wave MFMA||VALU overlap).
// ---------------------------------------------------------------------------
__global__ __launch_bounds__(256, 2) void attn_mfma(
    const u16* __restrict__ qkvb, const u16* __restrict__ vt,
    u16* __restrict__ attnb) {
  __shared__ u16 Qs[128 * 64];
  __shared__ u16 Ks2[2][64 * 64];
  __shared__ u16 Vs2[2][64 * 64];

  const int qt = blockIdx.x, head = blockIdx.y, b = blockIdx.z;
  const int tid = threadIdx.x, w = tid >> 6, l = tid & 63;
  const int lq = l & 31, hw = l >> 5;
  const size_t sb = (size_t)b * 2048;
  const f32x16 z16 = {};

  const int bi0 = tid, bi1 = 256 + tid;
  const int sr0 = bi0 >> 3, slb0 = (bi0 & 7) ^ (sr0 & 7);
  const int sr1 = bi1 >> 3, slb1 = (bi1 & 7) ^ (sr1 & 7);

  const u16* kbase = qkvb + sb * 3072 + 1024 + head * 64;
  const u16* vbase = vt + ((size_t)((b << 4) + head) << 6) * 2048;

  // per-thread staging sources (K row-major in qkv; V^T row-major in vt)
  const u16* kp0 = kbase + (size_t)sr0 * 3072 + slb0 * 8;
  const u16* kp1 = kbase + (size_t)sr1 * 3072 + slb1 * 8;
  const u16* vp0 = vbase + (size_t)sr0 * 2048 + slb0 * 8;
  const u16* vp1 = vbase + (size_t)sr1 * 2048 + slb1 * 8;

  // stage Q[128 q][64 d] (block-swizzle ^ (row&7))
  {
    const u16* qb = qkvb + (sb + (size_t)qt * 128) * 3072 + head * 64;
#pragma unroll
    for (int j = 0; j < 4; ++j) {
      const int qi = tid + 256 * j;
      const int r = qi >> 3, blk = (qi & 7) ^ (r & 7);
      g2l16(qb + (size_t)r * 3072 + blk * 8, (char*)Qs + qi * 16);
    }
  }
  __syncthreads();

  // Q frags (B-operand): col q = lq (abs row 32w+lq), k = d = 16dc+8hw+e
  bf16x8 qf[4];
  {
    const int row = (w << 5) + lq;
#pragma unroll
    for (int dc = 0; dc < 4; ++dc)
      qf[dc] = *(const bf16x8*)((const char*)Qs + row * 128 +
                                (((2 * dc + hw) ^ (row & 7)) << 4));
  }

  float m_run = -1e30f, l_run = 0.f;
  f32x16 o0 = z16, o1 = z16;
  const int xsw = lq & 7;

  for (int kt = 0; kt < 16; ++kt) {
    const size_t ko = (size_t)kt << 7;  // 128 keys per barrier pair
    __syncthreads();                    // all waves done reading prev tiles
    g2l16(kp0 + ko * 3072, (char*)Ks2[0] + bi0 * 16);
    g2l16(kp1 + ko * 3072, (char*)Ks2[0] + bi1 * 16);
    g2l16(kp0 + (ko + 64) * 3072, (char*)Ks2[1] + bi0 * 16);
    g2l16(kp1 + (ko + 64) * 3072, (char*)Ks2[1] + bi1 * 16);
    g2l16(vp0 + ko, (char*)Vs2[0] + bi0 * 16);
    g2l16(vp1 + ko, (char*)Vs2[0] + bi1 * 16);
    g2l16(vp0 + ko + 64, (char*)Vs2[1] + bi0 * 16);
    g2l16(vp1 + ko + 64, (char*)Vs2[1] + bi1 * 16);
    __syncthreads();                    // drain staging

    const char* K0 = (const char*)Ks2[0];
    const char* K1 = (const char*)Ks2[1];
    const char* V0 = (const char*)Vs2[0];
    const char* V1 = (const char*)Vs2[1];

    // QK^T for BOTH sub-tiles: 16 independent MFMAs, 4 accumulators
    f32x16 s00 = z16, s01 = z16, s10 = z16, s11 = z16;
#pragma unroll
    for (int dc = 0; dc < 4; ++dc) {
      const int off = (((2 * dc + hw) ^ xsw) << 4);
      s00 = MFMA32(*(const bf16x8*)(K0 + lq * 128 + off), qf[dc], s00);
      s01 = MFMA32(*(const bf16x8*)(K0 + (32 + lq) * 128 + off), qf[dc], s01);
      s10 = MFMA32(*(const bf16x8*)(K1 + lq * 128 + off), qf[dc], s10);
      s11 = MFMA32(*(const bf16x8*)(K1 + (32 + lq) * 128 + off), qf[dc], s11);
    }

    // one softmax window per 128 keys: joint max, single defer-check
    float mx = s00[0];
#pragma unroll
    for (int i = 1; i < 16; ++i) mx = fmaxf(mx, s00[i]);
#pragma unroll
    for (int i = 0; i < 16; ++i) mx = fmaxf(mx, s01[i]);
#pragma unroll
    for (int i = 0; i < 16; ++i) mx = fmaxf(mx, s10[i]);
#pragma unroll
    for (int i = 0; i < 16; ++i) mx = fmaxf(mx, s11[i]);
    {
      const u32x2 r = pl32swap(__float_as_uint(mx), __float_as_uint(mx));
      mx = fmaxf(__uint_as_float(r.x), __uint_as_float(r.y));
    }
    if (!__all(mx - m_run <= 8.f)) {  // defer-max: rescale only when max grows
      const float m_new = fmaxf(m_run, mx);
      const float resc = exp2fast(m_run - m_new);
      float rs[16];
#pragma unroll
      for (int r = 0; r < 16; ++r)
        rs[r] = __shfl(resc, (r & 3) + 8 * (r >> 2) + 4 * hw);
#pragma unroll
      for (int r = 0; r < 16; ++r) { o0[r] *= rs[r]; o1[r] *= rs[r]; }
      l_run *= resc;
      m_run = m_new;
    }

    float lsum = 0.f;

    // ---- sub0: exp + pack + PV (sub1's VALU below can fill PV0's shadow) ---
#pragma unroll
    for (int i = 0; i < 16; ++i) { s00[i] = exp2fast(s00[i] - m_run); lsum += s00[i]; }
#pragma unroll
    for (int i = 0; i < 16; ++i) { s01[i] = exp2fast(s01[i] - m_run); lsum += s01[i]; }
    bf16x8 pa[4];
#pragma unroll
    for (int kc = 0; kc < 4; ++kc) {
      const f32x16 s = (kc < 2) ? s00 : s01;
      const int q0 = (kc & 1) * 8;
      const u32x2 rA = pl32swap(pk2(s[q0 + 0], s[q0 + 1]), pk2(s[q0 + 4], s[q0 + 5]));
      const u32x2 rB = pl32swap(pk2(s[q0 + 2], s[q0 + 3]), pk2(s[q0 + 6], s[q0 + 7]));
      const u32x4 wds = {rA.x, rB.x, rA.y, rB.y};
      pa[kc] = __builtin_bit_cast(bf16x8, wds);
    }
#pragma unroll
    for (int kc = 0; kc < 4; ++kc) {
      const int off = (((2 * kc + hw) ^ xsw) << 4);
      o0 = MFMA32(pa[kc], *(const bf16x8*)(V0 + lq * 128 + off), o0);
      o1 = MFMA32(pa[kc], *(const bf16x8*)(V0 + (32 + lq) * 128 + off), o1);
    }

    // ---- sub1: exp + pack + PV -------------------------------------------
#pragma unroll
    for (int i = 0; i < 16; ++i) { s10[i] = exp2fast(s10[i] - m_run); lsum += s10[i]; }
#pragma unroll
    for (int i = 0; i < 16; ++i) { s11[i] = exp2fast(s11[i] - m_run); lsum += s11[i]; }
    bf16x8 pb[4];
#pragma unroll
    for (int kc = 0; kc < 4; ++kc) {
      const f32x16 s = (kc < 2) ? s10 : s11;
      const int q0 = (kc & 1) * 8;
      const u32x2 rA = pl32swap(pk2(s[q0 + 0], s[q0 + 1]), pk2(s[q0 + 4], s[q0 + 5]));
      const u32x2 rB = pl32swap(pk2(s[q0 + 2], s[q0 + 3]), pk2(s[q0 + 6], s[q0 + 7]));
      const u32x4 wds = {rA.x, rB.x, rA.y, rB.y};
      pb[kc] = __builtin_bit_cast(bf16x8, wds);
    }
#pragma unroll
    for (int kc = 0; kc < 4; ++kc) {
      const int off = (((2 * kc + hw) ^ xsw) << 4);
      o0 = MFMA32(pb[kc], *(const bf16x8*)(V1 + lq * 128 + off), o0);
      o1 = MFMA32(pb[kc], *(const bf16x8*)(V1 + (32 + lq) * 128 + off), o1);
    }

    l_run += lsum;  // per-half partial; combined once in epilogue
  }

  // combine per-half l partials, then epilogue
  {
    const u32x2 r = pl32swap(__float_as_uint(l_run), __float_as_uint(l_run));
    l_run = __uint_as_float(r.x) + __uint_as_float(r.y);
  }
  const float invl = 1.f / l_run;
  u16* ob = attnb + (sb + (size_t)qt * 128 + (w << 5)) * 1024 + head * 64;
#pragma unroll
  for (int r = 0; r < 16; ++r) {
    const int qo = (r & 3) + 8 * (r >> 2) + 4 * hw;
    const float iv = __shfl(invl, qo);
    ob[(size_t)qo * 1024 + lq] = f2bf(o0[r] * iv);
    ob[(size_t)qo * 1024 + 32 + lq] = f2bf(o1[r] * iv);
  }
}

// ---------------------------------------------------------------------------
extern "C" void kernel_launch(void* const* d_in, const int* in_sizes, int n_in,
                              void* d_out, int out_size, void* d_ws, size_t ws_size,
                              hipStream_t stream) {
  const float* x     = (const float*)d_in[0];  // [2,2048,1024]
  const float* w_qkv = (const float*)d_in[1];  // [1024,3072]
  const float* b_qkv = (const float*)d_in[2];  // [3072]
  const float* w_o   = (const float*)d_in[3];  // [1024,1024]
  const float* b_o   = (const float*)d_in[4];  // [1024]
  float* out = (float*)d_out;

  // workspace (bf16), 56 MB total
  u16* xb    = (u16*)d_ws;                       // 4096*1024
  u16* wqkvt = xb + (size_t)4096 * 1024;         // 3072*1024 (B^T)
  u16* wot   = wqkvt + (size_t)3072 * 1024;      // 1024*1024 (B^T)
  u16* qkvb  = wot + (size_t)1024 * 1024;        // 4096*3072
  u16* vtb   = qkvb + (size_t)4096 * 3072;       // 2*16*64*2048
  u16* attnb = vtb + (size_t)2 * 16 * 64 * 2048; // 4096*1024

  xcvt<<<dim3(2048), dim3(256), 0, stream>>>(x, xb, 4096 * 1024 / 8);
  // Q-columns (first 1024 of 3072) pre-scaled by 0.125*log2e -> exp2-domain scores
  wtrans<<<dim3(96, 32), dim3(256), 0, stream>>>(w_qkv, wqkvt, 1024, 3072, 1024, C_SCALE);
  wtrans<<<dim3(32, 32), dim3(256), 0, stream>>>(w_o, wot, 1024, 1024, 0, 1.f);

  gemm_mfma<1><<<dim3(24, 32), dim3(256), 0, stream>>>(xb, wqkvt, b_qkv, qkvb, 3072, 1024, 1024, C_SCALE);

  vtrans<<<dim3(2048), dim3(256), 0, stream>>>(qkvb, vtb);
  attn_mfma<<<dim3(16, 16, 2), dim3(256), 0, stream>>>(qkvb, vtb, attnb);

  gemm_mfma<0><<<dim3(8, 32), dim3(256), 0, stream>>>(attnb, wot, b_o, out, 1024, 1024, 0, 1.f);
}

// Round 11
// 130.013 us; speedup vs baseline: 1.1175x; 1.0721x over previous
//
#include <hip/hip_runtime.h>
#include <hip/hip_bf16.h>

typedef unsigned int u32;
typedef unsigned short u16;
typedef __attribute__((ext_vector_type(8))) short bf16x8;   // MFMA A/B frag (8 bf16)
typedef __attribute__((ext_vector_type(4))) float f32x4;
typedef __attribute__((ext_vector_type(16))) float f32x16;  // 32x32 MFMA C/D frag
typedef __attribute__((ext_vector_type(8))) u16 u16x8;
typedef __attribute__((ext_vector_type(2))) u32 u32x2;
typedef __attribute__((ext_vector_type(4))) u32 u32x4;

#define MFMA16(A, B, C) __builtin_amdgcn_mfma_f32_16x16x32_bf16(A, B, C, 0, 0, 0)
#define MFMA32(A, B, C) __builtin_amdgcn_mfma_f32_32x32x16_bf16(A, B, C, 0, 0, 0)

// 0.125 (1/sqrt(64)) * log2(e): folded into Q weights/bias -> scores in exp2 domain
#define C_SCALE 0.1803368801111244f

__device__ __forceinline__ u16 f2bf(float f) {   // RNE via native cast
  __hip_bfloat16 h = __float2bfloat16(f);
  u16 u;
  __builtin_memcpy(&u, &h, 2);
  return u;
}

__device__ __forceinline__ u32 pk2(float a, float b) {  // 2xbf16 pack (cvt_pk-able)
  return (u32)f2bf(a) | ((u32)f2bf(b) << 16);
}

__device__ __forceinline__ float exp2fast(float x) {
#if __has_builtin(__builtin_amdgcn_exp2f)
  return __builtin_amdgcn_exp2f(x);
#else
  return exp2f(x);
#endif
}

__device__ __forceinline__ u32x2 pl32swap(u32 a, u32 b) {
  return __builtin_amdgcn_permlane32_swap(a, b, false, false);
}

__device__ __forceinline__ void g2l16(const void* g, void* l) {
  __builtin_amdgcn_global_load_lds(
      (const __attribute__((address_space(1))) u32*)g,
      (__attribute__((address_space(3))) u32*)l, 16, 0, 0);
}

// ---------------------------------------------------------------------------
// Fused prep: [0,2048) xcvt blocks; [2048,5120) w_qkv transpose; [5120,6144)
// w_o transpose.  One launch instead of three.
// ---------------------------------------------------------------------------
__device__ __forceinline__ void wtrans_tile(const float* __restrict__ in,
                                            u16* __restrict__ out, int R, int C,
                                            int scale_n, float scale,
                                            int c0, int r0, float (*t)[33]) {
  const int tr = threadIdx.x >> 3, tc = (threadIdx.x & 7) << 2;
  const float4 v = *(const float4*)(in + (size_t)(r0 + tr) * C + c0 + tc);
  t[tr][tc] = v.x; t[tr][tc + 1] = v.y; t[tr][tc + 2] = v.z; t[tr][tc + 3] = v.w;
  __syncthreads();
  const float s = (c0 + tr < scale_n) ? scale : 1.f;
  u32 p0 = pk2(t[tc][tr] * s, t[tc + 1][tr] * s);
  u32 p1 = pk2(t[tc + 2][tr] * s, t[tc + 3][tr] * s);
  u32* dst = (u32*)(out + (size_t)(c0 + tr) * R + r0 + tc);
  dst[0] = p0;
  dst[1] = p1;
}

__global__ __launch_bounds__(256) void prep(
    const float* __restrict__ x, u16* __restrict__ xb,
    const float* __restrict__ w_qkv, u16* __restrict__ wqkvt,
    const float* __restrict__ w_o, u16* __restrict__ wot) {
  __shared__ float t[32][33];
  const int bx = blockIdx.x;
  if (bx < 2048) {                       // xcvt: 4096*1024 fp32 -> bf16
    const int i = bx * 256 + threadIdx.x;
    const float4* p = (const float4*)x + (size_t)i * 2;
    const float4 a = p[0], b = p[1];
    u16x8 o;
    o[0] = f2bf(a.x); o[1] = f2bf(a.y); o[2] = f2bf(a.z); o[3] = f2bf(a.w);
    o[4] = f2bf(b.x); o[5] = f2bf(b.y); o[6] = f2bf(b.z); o[7] = f2bf(b.w);
    *((u16x8*)xb + i) = o;
  } else if (bx < 5120) {                // w_qkv -> B^T (Q cols pre-scaled)
    const int tb = bx - 2048;
    wtrans_tile(w_qkv, wqkvt, 1024, 3072, 1024, C_SCALE,
                (tb % 96) << 5, (tb / 96) << 5, t);
  } else {                               // w_o -> B^T
    const int tb = bx - 5120;
    wtrans_tile(w_o, wot, 1024, 1024, 0, 1.f,
                (tb % 32) << 5, (tb / 32) << 5, t);
  }
}

// ---------------------------------------------------------------------------
// bf16 MFMA GEMM: C[M,N] = A[M,K] @ Bt[N,K]^T + bias.  BM=128, BN templated
// (128 or 64), BK=32 — the round-9-verified staging/swizzle pattern exactly:
// rows of 4 16B-chunks, chunk lb = (bi&3) ^ ((row>>1)&3); 4 waves of
// 64 x (BN/2) each.
// ---------------------------------------------------------------------------
template <int BN, int OUT_BF16>
__global__ __launch_bounds__(256) void gemm_mfma(
    const u16* __restrict__ A, const u16* __restrict__ Bt,
    const float* __restrict__ bias, void* __restrict__ Cv, int N, int K,
    int bsn, float bsc) {
  constexpr int NI = BN / 32;            // B-frags per wave
  __shared__ u16 As[128 * 32];
  __shared__ u16 Bs[BN * 32];
  const int tid = threadIdx.x;
  const int l = tid & 63, g = l >> 4, lr = l & 15;
  const int w = tid >> 6;
  const int wm = (w >> 1) << 6, wn = (w & 1) * (BN / 2);
  const int bm = blockIdx.y << 7, bn = blockIdx.x * BN;

  f32x4 acc[4][NI];
  const f32x4 zero = {0.f, 0.f, 0.f, 0.f};
#pragma unroll
  for (int i = 0; i < 4; ++i)
#pragma unroll
    for (int j = 0; j < NI; ++j) acc[i][j] = zero;

  const int bi0 = tid, bi1 = 256 + tid;
  const int r0 = bi0 >> 2, lb0 = (bi0 & 3) ^ ((r0 >> 1) & 3);
  const int r1 = bi1 >> 2, lb1 = (bi1 & 3) ^ ((r1 >> 1) & 3);
  const u16* a0 = A + (size_t)(bm + r0) * K + lb0 * 8;
  const u16* a1 = A + (size_t)(bm + r1) * K + lb1 * 8;
  const u16* b0 = Bt + (size_t)(bn + r0) * K + lb0 * 8;
  const u16* b1 = Bt + (size_t)(bn + r1) * K + lb1 * 8;  // used only if BN==128

  const int swA = (lr >> 1) & 3;
  const int aoff = (wm + lr) * 64 + ((g ^ swA) << 4);
  const int boff = (wn + lr) * 64 + ((g ^ swA) << 4);

  for (int k0 = 0; k0 < K; k0 += 32) {
    __syncthreads();
    g2l16(a0 + k0, (char*)As + bi0 * 16);
    g2l16(a1 + k0, (char*)As + bi1 * 16);
    g2l16(b0 + k0, (char*)Bs + bi0 * 16);
    if constexpr (BN == 128) g2l16(b1 + k0, (char*)Bs + bi1 * 16);
    __syncthreads();
    bf16x8 af[4], bfv[NI];
#pragma unroll
    for (int mi = 0; mi < 4; ++mi)
      af[mi] = *(const bf16x8*)((const char*)As + aoff + mi * 1024);
#pragma unroll
    for (int ni = 0; ni < NI; ++ni)
      bfv[ni] = *(const bf16x8*)((const char*)Bs + boff + ni * 1024);
#pragma unroll
    for (int mi = 0; mi < 4; ++mi)
#pragma unroll
      for (int ni = 0; ni < NI; ++ni)
        acc[mi][ni] = MFMA16(af[mi], bfv[ni], acc[mi][ni]);
  }

  float bv[NI];
#pragma unroll
  for (int ni = 0; ni < NI; ++ni) {
    const int col = bn + wn + ni * 16 + lr;
    bv[ni] = bias[col] * (col < bsn ? bsc : 1.f);
  }
  const int crow = bm + wm + (g << 2);
  const int ccol = bn + wn + lr;
  if (OUT_BF16) {
    u16* C = (u16*)Cv;
#pragma unroll
    for (int mi = 0; mi < 4; ++mi)
#pragma unroll
      for (int ni = 0; ni < NI; ++ni)
#pragma unroll
        for (int j = 0; j < 4; ++j)
          C[(size_t)(crow + mi * 16 + j) * N + ccol + ni * 16] =
              f2bf(acc[mi][ni][j] + bv[ni]);
  } else {
    float* C = (float*)Cv;
#pragma unroll
    for (int mi = 0; mi < 4; ++mi)
#pragma unroll
      for (int ni = 0; ni < NI; ++ni)
#pragma unroll
        for (int j = 0; j < 4; ++j)
          C[(size_t)(crow + mi * 16 + j) * N + ccol + ni * 16] =
              acc[mi][ni][j] + bv[ni];
  }
}

// ---------------------------------------------------------------------------
// V-transpose: qkv_b[.., 2048+h*64+d] -> vt[(b*16+h)*64+d][s]  (bf16)
// ---------------------------------------------------------------------------
__global__ __launch_bounds__(256) void vtrans(const u16* __restrict__ qkvb,
                                              u16* __restrict__ vt) {
  const int wid = (blockIdx.x << 2) + (threadIdx.x >> 6);
  const int l = threadIdx.x & 63;
  const int dc = wid & 7, st = (wid >> 3) & 31, h = (wid >> 8) & 15, b = wid >> 12;
  const int s = (st << 6) + l;
  const u16x8 v = *(const u16x8*)(qkvb + (size_t)(b * 2048 + s) * 3072 + 2048 + h * 64 + dc * 8);
  u16* dst = vt + ((size_t)(((b << 4) + h) << 6) + (dc << 3)) * 2048 + s;
#pragma unroll
  for (int j = 0; j < 8; ++j) dst[(size_t)j * 2048] = v[j];
}

// ---------------------------------------------------------------------------
// Flash attention (unchanged from round 9): 32x32x16 MFMA, swapped QK^T,
// in-register softmax + P, KVBLK=128, wide softmax window, VALU||MFMA tail.
// ---------------------------------------------------------------------------
__global__ __launch_bounds__(256, 2) void attn_mfma(
    const u16* __restrict__ qkvb, const u16* __restrict__ vt,
    u16* __restrict__ attnb) {
  __shared__ u16 Qs[128 * 64];
  __shared__ u16 Ks2[2][64 * 64];
  __shared__ u16 Vs2[2][64 * 64];

  const int qt = blockIdx.x, head = blockIdx.y, b = blockIdx.z;
  const int tid = threadIdx.x, w = tid >> 6, l = tid & 63;
  const int lq = l & 31, hw = l >> 5;
  const size_t sb = (size_t)b * 2048;
  const f32x16 z16 = {};

  const int bi0 = tid, bi1 = 256 + tid;
  const int sr0 = bi0 >> 3, slb0 = (bi0 & 7) ^ (sr0 & 7);
  const int sr1 = bi1 >> 3, slb1 = (bi1 & 7) ^ (sr1 & 7);

  const u16* kbase = qkvb + sb * 3072 + 1024 + head * 64;
  const u16* vbase = vt + ((size_t)((b << 4) + head) << 6) * 2048;

  const u16* kp0 = kbase + (size_t)sr0 * 3072 + slb0 * 8;
  const u16* kp1 = kbase + (size_t)sr1 * 3072 + slb1 * 8;
  const u16* vp0 = vbase + (size_t)sr0 * 2048 + slb0 * 8;
  const u16* vp1 = vbase + (size_t)sr1 * 2048 + slb1 * 8;

  {
    const u16* qb = qkvb + (sb + (size_t)qt * 128) * 3072 + head * 64;
#pragma unroll
    for (int j = 0; j < 4; ++j) {
      const int qi = tid + 256 * j;
      const int r = qi >> 3, blk = (qi & 7) ^ (r & 7);
      g2l16(qb + (size_t)r * 3072 + blk * 8, (char*)Qs + qi * 16);
    }
  }
  __syncthreads();

  bf16x8 qf[4];
  {
    const int row = (w << 5) + lq;
#pragma unroll
    for (int dc = 0; dc < 4; ++dc)
      qf[dc] = *(const bf16x8*)((const char*)Qs + row * 128 +
                                (((2 * dc + hw) ^ (row & 7)) << 4));
  }

  float m_run = -1e30f, l_run = 0.f;
  f32x16 o0 = z16, o1 = z16;
  const int xsw = lq & 7;

  for (int kt = 0; kt < 16; ++kt) {
    const size_t ko = (size_t)kt << 7;
    __syncthreads();
    g2l16(kp0 + ko * 3072, (char*)Ks2[0] + bi0 * 16);
    g2l16(kp1 + ko * 3072, (char*)Ks2[0] + bi1 * 16);
    g2l16(kp0 + (ko + 64) * 3072, (char*)Ks2[1] + bi0 * 16);
    g2l16(kp1 + (ko + 64) * 3072, (char*)Ks2[1] + bi1 * 16);
    g2l16(vp0 + ko, (char*)Vs2[0] + bi0 * 16);
    g2l16(vp1 + ko, (char*)Vs2[0] + bi1 * 16);
    g2l16(vp0 + ko + 64, (char*)Vs2[1] + bi0 * 16);
    g2l16(vp1 + ko + 64, (char*)Vs2[1] + bi1 * 16);
    __syncthreads();

    const char* K0 = (const char*)Ks2[0];
    const char* K1 = (const char*)Ks2[1];
    const char* V0 = (const char*)Vs2[0];
    const char* V1 = (const char*)Vs2[1];

    f32x16 s00 = z16, s01 = z16, s10 = z16, s11 = z16;
#pragma unroll
    for (int dc = 0; dc < 4; ++dc) {
      const int off = (((2 * dc + hw) ^ xsw) << 4);
      s00 = MFMA32(*(const bf16x8*)(K0 + lq * 128 + off), qf[dc], s00);
      s01 = MFMA32(*(const bf16x8*)(K0 + (32 + lq) * 128 + off), qf[dc], s01);
      s10 = MFMA32(*(const bf16x8*)(K1 + lq * 128 + off), qf[dc], s10);
      s11 = MFMA32(*(const bf16x8*)(K1 + (32 + lq) * 128 + off), qf[dc], s11);
    }

    float mx = s00[0];
#pragma unroll
    for (int i = 1; i < 16; ++i) mx = fmaxf(mx, s00[i]);
#pragma unroll
    for (int i = 0; i < 16; ++i) mx = fmaxf(mx, s01[i]);
#pragma unroll
    for (int i = 0; i < 16; ++i) mx = fmaxf(mx, s10[i]);
#pragma unroll
    for (int i = 0; i < 16; ++i) mx = fmaxf(mx, s11[i]);
    {
      const u32x2 r = pl32swap(__float_as_uint(mx), __float_as_uint(mx));
      mx = fmaxf(__uint_as_float(r.x), __uint_as_float(r.y));
    }
    if (!__all(mx - m_run <= 8.f)) {
      const float m_new = fmaxf(m_run, mx);
      const float resc = exp2fast(m_run - m_new);
      float rs[16];
#pragma unroll
      for (int r = 0; r < 16; ++r)
        rs[r] = __shfl(resc, (r & 3) + 8 * (r >> 2) + 4 * hw);
#pragma unroll
      for (int r = 0; r < 16; ++r) { o0[r] *= rs[r]; o1[r] *= rs[r]; }
      l_run *= resc;
      m_run = m_new;
    }

    float lsum = 0.f;

#pragma unroll
    for (int i = 0; i < 16; ++i) { s00[i] = exp2fast(s00[i] - m_run); lsum += s00[i]; }
#pragma unroll
    for (int i = 0; i < 16; ++i) { s01[i] = exp2fast(s01[i] - m_run); lsum += s01[i]; }
    bf16x8 pa[4];
#pragma unroll
    for (int kc = 0; kc < 4; ++kc) {
      const f32x16 s = (kc < 2) ? s00 : s01;
      const int q0 = (kc & 1) * 8;
      const u32x2 rA = pl32swap(pk2(s[q0 + 0], s[q0 + 1]), pk2(s[q0 + 4], s[q0 + 5]));
      const u32x2 rB = pl32swap(pk2(s[q0 + 2], s[q0 + 3]), pk2(s[q0 + 6], s[q0 + 7]));
      const u32x4 wds = {rA.x, rB.x, rA.y, rB.y};
      pa[kc] = __builtin_bit_cast(bf16x8, wds);
    }
#pragma unroll
    for (int kc = 0; kc < 4; ++kc) {
      const int off = (((2 * kc + hw) ^ xsw) << 4);
      o0 = MFMA32(pa[kc], *(const bf16x8*)(V0 + lq * 128 + off), o0);
      o1 = MFMA32(pa[kc], *(const bf16x8*)(V0 + (32 + lq) * 128 + off), o1);
    }

#pragma unroll
    for (int i = 0; i < 16; ++i) { s10[i] = exp2fast(s10[i] - m_run); lsum += s10[i]; }
#pragma unroll
    for (int i = 0; i < 16; ++i) { s11[i] = exp2fast(s11[i] - m_run); lsum += s11[i]; }
    bf16x8 pb[4];
#pragma unroll
    for (int kc = 0; kc < 4; ++kc) {
      const f32x16 s = (kc < 2) ? s10 : s11;
      const int q0 = (kc & 1) * 8;
      const u32x2 rA = pl32swap(pk2(s[q0 + 0], s[q0 + 1]), pk2(s[q0 + 4], s[q0 + 5]));
      const u32x2 rB = pl32swap(pk2(s[q0 + 2], s[q0 + 3]), pk2(s[q0 + 6], s[q0 + 7]));
      const u32x4 wds = {rA.x, rB.x, rA.y, rB.y};
      pb[kc] = __builtin_bit_cast(bf16x8, wds);
    }
#pragma unroll
    for (int kc = 0; kc < 4; ++kc) {
      const int off = (((2 * kc + hw) ^ xsw) << 4);
      o0 = MFMA32(pb[kc], *(const bf16x8*)(V1 + lq * 128 + off), o0);
      o1 = MFMA32(pb[kc], *(const bf16x8*)(V1 + (32 + lq) * 128 + off), o1);
    }

    l_run += lsum;
  }

  {
    const u32x2 r = pl32swap(__float_as_uint(l_run), __float_as_uint(l_run));
    l_run = __uint_as_float(r.x) + __uint_as_float(r.y);
  }
  const float invl = 1.f / l_run;
  u16* ob = attnb + (sb + (size_t)qt * 128 + (w << 5)) * 1024 + head * 64;
#pragma unroll
  for (int r = 0; r < 16; ++r) {
    const int qo = (r & 3) + 8 * (r >> 2) + 4 * hw;
    const float iv = __shfl(invl, qo);
    ob[(size_t)qo * 1024 + lq] = f2bf(o0[r] * iv);
    ob[(size_t)qo * 1024 + 32 + lq] = f2bf(o1[r] * iv);
  }
}

// ---------------------------------------------------------------------------
extern "C" void kernel_launch(void* const* d_in, const int* in_sizes, int n_in,
                              void* d_out, int out_size, void* d_ws, size_t ws_size,
                              hipStream_t stream) {
  const float* x     = (const float*)d_in[0];  // [2,2048,1024]
  const float* w_qkv = (const float*)d_in[1];  // [1024,3072]
  const float* b_qkv = (const float*)d_in[2];  // [3072]
  const float* w_o   = (const float*)d_in[3];  // [1024,1024]
  const float* b_o   = (const float*)d_in[4];  // [1024]
  float* out = (float*)d_out;

  // workspace (bf16), 56 MB total
  u16* xb    = (u16*)d_ws;                       // 4096*1024
  u16* wqkvt = xb + (size_t)4096 * 1024;         // 3072*1024 (B^T)
  u16* wot   = wqkvt + (size_t)3072 * 1024;      // 1024*1024 (B^T)
  u16* qkvb  = wot + (size_t)1024 * 1024;        // 4096*3072
  u16* vtb   = qkvb + (size_t)4096 * 3072;       // 2*16*64*2048
  u16* attnb = vtb + (size_t)2 * 16 * 64 * 2048; // 4096*1024

  // fused prep: xcvt (2048 blocks) + w_qkv^T (3072) + w_o^T (1024)
  prep<<<dim3(6144), dim3(256), 0, stream>>>(x, xb, w_qkv, wqkvt, w_o, wot);

  gemm_mfma<128, 1><<<dim3(24, 32), dim3(256), 0, stream>>>(
      xb, wqkvt, b_qkv, qkvb, 3072, 1024, 1024, C_SCALE);

  vtrans<<<dim3(2048), dim3(256), 0, stream>>>(qkvb, vtb);
  attn_mfma<<<dim3(16, 16, 2), dim3(256), 0, stream>>>(qkvb, vtb, attnb);

  gemm_mfma<64, 0><<<dim3(16, 32), dim3(256), 0, stream>>>(
      attnb, wot, b_o, out, 1024, 1024, 0, 1.f);
}